// Round 1
// baseline (104.116 us; speedup 1.0000x reference)
//
#include <hip/hip_runtime.h>
#include <hip/hip_bf16.h>

// Problem constants (from reference):
//   BS=256, M=64 tokens (8x8), NUM_EMB=1024, LATENT(C)=1024
//   out[b, c, g1, g2] = weight[idx[b, g1*8+g2], c]   (fp32, 64 MiB total)
//
// Strategy: write-side coalescing. One block = one (batch, 16-channel tile).
// Thread t writes float4 at out[(b*C + c0 + (t>>4))*64 + (t&15)*4] -> each
// wave's store is 1 KiB fully contiguous. Gathered weight reads are scalar
// but L2-resident (weight = 4 MiB); 64 indices/block staged in LDS.

#define BS 256
#define M 64
#define C 1024

__global__ __launch_bounds__(256) void gather_transpose_kernel(
    const int* __restrict__ idx,      // [BS*M] int32
    const float* __restrict__ w,      // [NUM_EMB, C] fp32
    float* __restrict__ out)          // [BS, C, 8, 8] fp32
{
    // grid.x = BS * (C/16) = 256 * 64 = 16384 blocks
    const int b  = blockIdx.x >> 6;          // 64 channel-tiles per batch
    const int c0 = (blockIdx.x & 63) << 4;   // 16 channels per block

    __shared__ int s_idx[M];
    const int t = threadIdx.x;
    if (t < M) s_idx[t] = idx[b * M + t];
    __syncthreads();

    const int m4 = t & 15;          // which group of 4 tokens (m = 4*m4 .. 4*m4+3)
    const int c  = c0 + (t >> 4);   // channel handled by this thread
    const int m  = m4 << 2;

    // 4 gathered reads (different codebook rows, same column c)
    const int r0 = s_idx[m + 0];
    const int r1 = s_idx[m + 1];
    const int r2 = s_idx[m + 2];
    const int r3 = s_idx[m + 3];

    float4 v;
    v.x = w[r0 * C + c];
    v.y = w[r1 * C + c];
    v.z = w[r2 * C + c];
    v.w = w[r3 * C + c];

    // out[(b*C + c) * 64 + m], 16B-aligned (m multiple of 4)
    float4* dst = (float4*)(out + ((size_t)(b * C + c) << 6) + m);
    *dst = v;
}

extern "C" void kernel_launch(void* const* d_in, const int* in_sizes, int n_in,
                              void* d_out, int out_size, void* d_ws, size_t ws_size,
                              hipStream_t stream) {
    const int*   idx = (const int*)d_in[0];    // encoding_indices [256, 64]
    const float* w   = (const float*)d_in[1];  // weight [1024, 1024]
    float*       out = (float*)d_out;          // [256, 1024, 8, 8]

    dim3 grid(BS * (C / 16));
    dim3 block(256);
    gather_transpose_kernel<<<grid, block, 0, stream>>>(idx, w, out);
}

// Round 2
// 79.534 us; speedup vs baseline: 1.3091x; 1.3091x over previous
//
#include <hip/hip_runtime.h>
#include <hip/hip_bf16.h>

// out[b, c, m] = weight[idx[b, m], c]   b<256, c<1024, m<64  (fp32, 64 MiB out)
//
// Per-block 64x64 (m x c) LDS transpose:
//  - block = (batch b, 64-channel tile c0). grid = 256*16 = 4096.
//  - Load: quarter-wave (16 lanes) reads one gathered row's 256B contiguous
//    (float4) -> full cacheline utilization (vs 16B/line in the scalar-gather
//    version that ran 104us).
//  - LDS tile stored transposed [cc][m], PAD=65: both scalar phases are
//    2 lanes/bank = conflict-free (m136).
//  - Store: 16 KiB fully contiguous per block (c-tile and m both contiguous
//    in the output), float4 per lane.

#define BS   256
#define M    64
#define C    1024
#define PAD  65   // 65 % 32 == 1 -> bank stride 1 for both access phases

__global__ __launch_bounds__(256) void gather_transpose_kernel(
    const int* __restrict__ idx,      // [BS*M] int32
    const float* __restrict__ w,      // [NUM_EMB, C] fp32
    float* __restrict__ out)          // [BS, C, 8, 8] fp32
{
    const int b  = blockIdx.x >> 4;          // 16 channel-tiles per batch
    const int c0 = (blockIdx.x & 15) << 6;   // 64 channels per block

    __shared__ int   s_idx[M];
    __shared__ float tile[M * PAD];          // [cc][m], transposed

    const int t = threadIdx.x;
    if (t < M) s_idx[t] = idx[b * M + t];
    __syncthreads();

    // ---- load phase: gather rows, coalesced 256B per 16-lane group ----
    const int f = t & 15;                    // float4 index within the 64-ch slice
#pragma unroll
    for (int j = 0; j < 4; ++j) {
        const int m   = (t >> 4) + (j << 4); // token 0..63
        const int row = s_idx[m];
        const float4 v = *(const float4*)(w + row * C + c0 + (f << 2));
        tile[((f << 2) + 0) * PAD + m] = v.x;
        tile[((f << 2) + 1) * PAD + m] = v.y;
        tile[((f << 2) + 2) * PAD + m] = v.z;
        tile[((f << 2) + 3) * PAD + m] = v.w;
    }
    __syncthreads();

    // ---- store phase: 16 KiB contiguous per block ----
    float* obase = out + (((size_t)(b * C + c0)) << 6);
#pragma unroll
    for (int j = 0; j < 4; ++j) {
        const int fo = (j << 8) + t;         // float4 slot 0..1023
        const int cc = fo >> 4;              // channel within tile
        const int m  = (fo & 15) << 2;       // token group of 4
        float4 v;
        v.x = tile[cc * PAD + m + 0];
        v.y = tile[cc * PAD + m + 1];
        v.z = tile[cc * PAD + m + 2];
        v.w = tile[cc * PAD + m + 3];
        *(float4*)(obase + (cc << 6) + m) = v;
    }
}

extern "C" void kernel_launch(void* const* d_in, const int* in_sizes, int n_in,
                              void* d_out, int out_size, void* d_ws, size_t ws_size,
                              hipStream_t stream) {
    const int*   idx = (const int*)d_in[0];    // encoding_indices [256, 64]
    const float* w   = (const float*)d_in[1];  // weight [1024, 1024]
    float*       out = (float*)d_out;          // [256, 1024, 8, 8]

    dim3 grid(BS * (C / 64));  // 4096 blocks
    dim3 block(256);
    gather_transpose_kernel<<<grid, block, 0, stream>>>(idx, w, out);
}